// Round 4
// baseline (147.013 us; speedup 1.0000x reference)
//
#include <hip/hip_runtime.h>

// SSIM per-channel statistics — single fused kernel, per-channel completion.
// Input: I1, I2 each (32, 3, 512, 512) fp32. Output: (32, 3) fp32 = 96 values.
// Per channel (n = 512*512): Sx, Sy, Sxx, Syy, Sxy -> closed-form SSIM.
//
// Stage-1 structure identical to the proven R1/R3 config: 96 ch * 32 blocks
// = 3072 blocks x 256 threads, 8 float4 per thread per input.
// Fusion: each block atomicAdds its CHANNEL's counter (96 addresses, 32 adds
// each — avoids R2's single-address 1536-atomic serial drain). The last block
// of each channel reduces that channel's 32 partials and writes out[ch].
// Channels complete independently; no global sync point.

#define N_CH 96
#define CH_F4 65536          // 262144 floats / 4 per channel
#define BPC 32               // blocks per channel
#define BLK_F4 2048          // CH_F4 / BPC
#define THREADS 256
#define ITERS 8              // BLK_F4 / THREADS

#define NBLOCKS (N_CH * BPC)         // 3072
#define CNT_OFF (NBLOCKS * 5)        // float index of counters in ws

__global__ __launch_bounds__(THREADS) void ssim_fused_kernel(
    const float4* __restrict__ I1, const float4* __restrict__ I2,
    float* __restrict__ ws, unsigned int* __restrict__ cnt,
    float* __restrict__ out)
{
    const int gid = blockIdx.x;
    const int ch  = gid >> 5;        // / BPC
    const int blk = gid & 31;        // % BPC
    const long base = (long)ch * CH_F4 + (long)blk * BLK_F4;
    const int t = threadIdx.x;

    float sx = 0.f, sy = 0.f, sxx = 0.f, syy = 0.f, sxy = 0.f;

#pragma unroll
    for (int i = 0; i < ITERS; ++i) {
        float4 a = I1[base + t + i * THREADS];
        float4 b = I2[base + t + i * THREADS];
        sx  += a.x + a.y + a.z + a.w;
        sy  += b.x + b.y + b.z + b.w;
        sxx += a.x * a.x + a.y * a.y + a.z * a.z + a.w * a.w;
        syy += b.x * b.x + b.y * b.y + b.z * b.z + b.w * b.w;
        sxy += a.x * b.x + a.y * b.y + a.z * b.z + a.w * b.w;
    }

    // 64-lane wave shuffle reduction
#pragma unroll
    for (int off = 32; off > 0; off >>= 1) {
        sx  += __shfl_down(sx,  off);
        sy  += __shfl_down(sy,  off);
        sxx += __shfl_down(sxx, off);
        syy += __shfl_down(syy, off);
        sxy += __shfl_down(sxy, off);
    }

    __shared__ float red[4][5];
    __shared__ bool  amLast;
    const int wave = t >> 6;
    const int lane = t & 63;
    if (lane == 0) {
        red[wave][0] = sx;  red[wave][1] = sy;  red[wave][2] = sxx;
        red[wave][3] = syy; red[wave][4] = sxy;
    }
    __syncthreads();
    if (t == 0) {
        float* o = ws + (size_t)gid * 5;
        o[0] = red[0][0] + red[1][0] + red[2][0] + red[3][0];
        o[1] = red[0][1] + red[1][1] + red[2][1] + red[3][1];
        o[2] = red[0][2] + red[1][2] + red[2][2] + red[3][2];
        o[3] = red[0][3] + red[1][3] + red[2][3] + red[3][3];
        o[4] = red[0][4] + red[1][4] + red[2][4] + red[3][4];
        __threadfence();                       // publish partials device-wide
        unsigned int done = atomicAdd(&cnt[ch], 1u);   // 32 adds per address
        amLast = (done == BPC - 1);
    }
    __syncthreads();

    if (amLast && t < 64) {
        __threadfence();                       // acquire all peers' partials
        float fx = 0.f, fy = 0.f, fxx = 0.f, fyy = 0.f, fxy = 0.f;
        if (t < BPC) {
            const float* p = ws + ((size_t)ch * BPC + t) * 5;
            fx = p[0]; fy = p[1]; fxx = p[2]; fyy = p[3]; fxy = p[4];
        }
#pragma unroll
        for (int off = 16; off > 0; off >>= 1) {
            fx  += __shfl_down(fx,  off);
            fy  += __shfl_down(fy,  off);
            fxx += __shfl_down(fxx, off);
            fyy += __shfl_down(fyy, off);
            fxy += __shfl_down(fxy, off);
        }
        if (t == 0) {
            const double n  = 262144.0;
            const double C1 = 0.0001, C2 = 0.001;
            double Sx = fx, Sy = fy, Sxx = fxx, Syy = fyy, Sxy = fxy;
            double mu1 = Sx / n;
            double mu2 = Sy / n;
            double s1  = (Sxx - Sx * Sx / n) / (n - 1.0);
            double s2  = (Syy - Sy * Sy / n) / (n - 1.0);
            double s12 = (Sxy - Sx * Sy / n) / n;
            double num = (2.0 * mu1 * mu2 + C1) * (2.0 * s12 + C2);
            double den = (mu1 * mu1 + mu2 * mu2 + C1) * (s1 + s2 + C2);
            out[ch] = (float)(num / den);
        }
    }
}

extern "C" void kernel_launch(void* const* d_in, const int* in_sizes, int n_in,
                              void* d_out, int out_size, void* d_ws, size_t ws_size,
                              hipStream_t stream)
{
    const float4* I1 = (const float4*)d_in[0];
    const float4* I2 = (const float4*)d_in[1];
    float* ws  = (float*)d_ws;                    // 3072*5 floats partials
    unsigned int* cnt = (unsigned int*)(ws + CNT_OFF);   // 96 counters
    float* out = (float*)d_out;                   // 96 floats

    // counters must be zero at every call (graph-capture-safe async memset)
    hipMemsetAsync(cnt, 0, N_CH * sizeof(unsigned int), stream);

    ssim_fused_kernel<<<NBLOCKS, THREADS, 0, stream>>>(I1, I2, ws, cnt, out);
}

// Round 5
// 35.568 us; speedup vs baseline: 4.1333x; 4.1333x over previous
//
#include <hip/hip_runtime.h>

// SSIM per-channel statistics — two-kernel version (proven R1 configuration).
// Input: I1, I2 each (32, 3, 512, 512) fp32. Output: (32, 3) fp32 = 96 values.
// Per channel (n = 512*512 = 262144): Sx, Sy, Sxx, Syy, Sxy -> closed-form SSIM.
//
// Verdict trail:
//  R1: this config                      -> 35.64 us (stage-1 ~6.17 TB/s = 98% of
//                                          6.29 TB/s achievable read BW; VALUBusy 6%)
//  R2: fused, 1 atomic counter          -> 87.7 us  (atomic/fence poison)
//  R3: ILP-widened loads                -> 35.71 us (neutral; already load-saturated)
//  R4: fused, 96 per-channel counters   -> 147 us   (atomic/fence poison confirmed;
//                                          scales with #fences, not contention)
// Conclusion: device-scope atomic signaling costs 100+ us here; the second
// dispatch costs only ~3.6 us. Two-kernel structure is the practical optimum.

#define N_CH 96
#define CH_F4 65536          // 262144 floats / 4 per channel
#define BLOCKS_PER_CH 32
#define BLK_F4 2048          // CH_F4 / BLOCKS_PER_CH
#define THREADS 256
#define ITERS 8              // BLK_F4 / THREADS

__global__ __launch_bounds__(THREADS) void ssim_partial_kernel(
    const float4* __restrict__ I1, const float4* __restrict__ I2,
    float* __restrict__ ws)
{
    const int gid = blockIdx.x;
    const int ch  = gid >> 5;        // / BLOCKS_PER_CH
    const int blk = gid & 31;        // % BLOCKS_PER_CH
    const long base = (long)ch * CH_F4 + (long)blk * BLK_F4;
    const int t = threadIdx.x;

    float sx = 0.f, sy = 0.f, sxx = 0.f, syy = 0.f, sxy = 0.f;

#pragma unroll
    for (int i = 0; i < ITERS; ++i) {
        float4 a = I1[base + t + i * THREADS];
        float4 b = I2[base + t + i * THREADS];
        sx  += a.x + a.y + a.z + a.w;
        sy  += b.x + b.y + b.z + b.w;
        sxx += a.x * a.x + a.y * a.y + a.z * a.z + a.w * a.w;
        syy += b.x * b.x + b.y * b.y + b.z * b.z + b.w * b.w;
        sxy += a.x * b.x + a.y * b.y + a.z * b.z + a.w * b.w;
    }

    // 64-lane wave shuffle reduction
#pragma unroll
    for (int off = 32; off > 0; off >>= 1) {
        sx  += __shfl_down(sx,  off);
        sy  += __shfl_down(sy,  off);
        sxx += __shfl_down(sxx, off);
        syy += __shfl_down(syy, off);
        sxy += __shfl_down(sxy, off);
    }

    __shared__ float red[4][5];
    const int wave = t >> 6;
    const int lane = t & 63;
    if (lane == 0) {
        red[wave][0] = sx;  red[wave][1] = sy;  red[wave][2] = sxx;
        red[wave][3] = syy; red[wave][4] = sxy;
    }
    __syncthreads();
    if (t == 0) {
        float* o = ws + (size_t)gid * 5;
        o[0] = red[0][0] + red[1][0] + red[2][0] + red[3][0];
        o[1] = red[0][1] + red[1][1] + red[2][1] + red[3][1];
        o[2] = red[0][2] + red[1][2] + red[2][2] + red[3][2];
        o[3] = red[0][3] + red[1][3] + red[2][3] + red[3][3];
        o[4] = red[0][4] + red[1][4] + red[2][4] + red[3][4];
    }
}

__global__ __launch_bounds__(64) void ssim_final_kernel(
    const float* __restrict__ ws, float* __restrict__ out)
{
    const int ch   = blockIdx.x;
    const int lane = threadIdx.x;   // 64 lanes

    float sx = 0.f, sy = 0.f, sxx = 0.f, syy = 0.f, sxy = 0.f;
    if (lane < BLOCKS_PER_CH) {
        const float* p = ws + ((size_t)ch * BLOCKS_PER_CH + lane) * 5;
        sx = p[0]; sy = p[1]; sxx = p[2]; syy = p[3]; sxy = p[4];
    }
#pragma unroll
    for (int off = 16; off > 0; off >>= 1) {
        sx  += __shfl_down(sx,  off);
        sy  += __shfl_down(sy,  off);
        sxx += __shfl_down(sxx, off);
        syy += __shfl_down(syy, off);
        sxy += __shfl_down(sxy, off);
    }
    if (lane == 0) {
        const double n  = 262144.0;
        const double C1 = 0.0001, C2 = 0.001;
        double Sx = sx, Sy = sy, Sxx = sxx, Syy = syy, Sxy = sxy;
        double mu1 = Sx / n;
        double mu2 = Sy / n;
        double s1  = (Sxx - Sx * Sx / n) / (n - 1.0);
        double s2  = (Syy - Sy * Sy / n) / (n - 1.0);
        double s12 = (Sxy - Sx * Sy / n) / n;
        double num = (2.0 * mu1 * mu2 + C1) * (2.0 * s12 + C2);
        double den = (mu1 * mu1 + mu2 * mu2 + C1) * (s1 + s2 + C2);
        out[ch] = (float)(num / den);
    }
}

extern "C" void kernel_launch(void* const* d_in, const int* in_sizes, int n_in,
                              void* d_out, int out_size, void* d_ws, size_t ws_size,
                              hipStream_t stream)
{
    const float4* I1 = (const float4*)d_in[0];
    const float4* I2 = (const float4*)d_in[1];
    float* ws  = (float*)d_ws;    // needs N_CH*BLOCKS_PER_CH*5*4 = 61440 B
    float* out = (float*)d_out;   // 96 floats

    ssim_partial_kernel<<<N_CH * BLOCKS_PER_CH, THREADS, 0, stream>>>(I1, I2, ws);
    ssim_final_kernel<<<N_CH, 64, 0, stream>>>(ws, out);
}